// Round 21
// baseline (141.270 us; speedup 1.0000x reference)
//
#include <hip/hip_runtime.h>
#include <hip/hip_bf16.h>
#include <stdint.h>

#define BN 4
#define CN 128
#define HN 96
#define WN 96
#define HW (HN*WN)
#define OCN 128
#define OFFC 18
#define EPSV 1e-6f
#define HP 98
#define WP 98
#define TILE 16
#define NWT (WN/TILE)
#define NWG (BN*HN*NWT)        // 2304 blocks

typedef __attribute__((ext_vector_type(8))) short bf16x8;
typedef __attribute__((ext_vector_type(4))) float f32x4;

__device__ __forceinline__ float lo16(uint32_t u) {
  union { uint32_t i; float f; } v; v.i = u << 16; return v.f;
}
__device__ __forceinline__ float hi16(uint32_t u) {
  union { uint32_t i; float f; } v; v.i = u & 0xffff0000u; return v.f;
}
__device__ __forceinline__ uint16_t f2b(float f) {
  union { float f; uint32_t i; } u; u.f = f;
  uint32_t r = u.i + 0x7fffu + ((u.i >> 16) & 1u);   // RNE
  return (uint16_t)(r >> 16);
}
__device__ __forceinline__ uint32_t pk2(float a, float b) {
  return (uint32_t)f2b(a) | ((uint32_t)f2b(b) << 16);
}
__device__ __forceinline__ int swz(int row, int c) { return c ^ ((row & 7) << 3); }

// async global->LDS, 16B per lane (HW: dst = lds_base + lane*16)
__device__ __forceinline__ void gload16(const uint16_t* g, uint16_t* l) {
  __builtin_amdgcn_global_load_lds(
      (const __attribute__((address_space(1))) uint32_t*)g,
      (__attribute__((address_space(3))) uint32_t*)l, 16, 0, 0);
}

__device__ __align__(16) uint16_t g_def[9 * 128 * 128];   // [k][oc][c]
__device__ __align__(16) uint16_t g_pw[128 * 128];        // [oc][c]
__device__ __align__(16) uint16_t g_off[32 * 1152];       // [j(pad32)][kk*128+c]
__device__ __align__(16) uint16_t g_xp[(size_t)BN * HP * WP * CN];  // channels-last, padded

__global__ __launch_bounds__(256)
void k_prep_w(const float* __restrict__ w_def, const float* __restrict__ w_pw,
              const float* __restrict__ w_off) {
  int i = blockIdx.x * 256 + threadIdx.x;
  if (i < 147456) {
    int k = i >> 14, rem = i & 16383, oc = rem >> 7, c = rem & 127;
    g_def[i] = f2b(w_def[((oc << 7) + c) * 9 + k]);
  } else if (i < 147456 + 16384) {
    int j = i - 147456;
    g_pw[j] = f2b(w_pw[j]);
  } else if (i < 147456 + 16384 + 36864) {
    int j = i - 163840;
    int row = j / 1152, col = j - row * 1152;
    int kk = col >> 7, c = col & 127;
    g_off[j] = (row < OFFC) ? f2b(w_off[((row << 7) + c) * 9 + kk]) : (uint16_t)0;
  }
}

__global__ __launch_bounds__(256)
void k_prep_x(const float* __restrict__ x) {
  __shared__ uint16_t trans[96][136];
  int blk = blockIdx.x;
  int y1 = blk % HP;
  int b  = blk / HP;
  int t = (int)threadIdx.x;
  uint16_t* dst = g_xp + ((size_t)(b * HP + y1) * WP) * CN;
  if (y1 == 0 || y1 == HP - 1) {
    for (int i = t; i < WP * CN / 8; i += 256)
      ((uint4*)dst)[i] = make_uint4(0, 0, 0, 0);
    return;
  }
  int y = y1 - 1;
  for (int i = t; i < CN * WN / 4; i += 256) {
    int c = i / 24, xq = i - c * 24;
    float4 f = *(const float4*)&x[((size_t)(b * CN + c) * HN + y) * WN + xq * 4];
    trans[xq * 4 + 0][c] = f2b(f.x);
    trans[xq * 4 + 1][c] = f2b(f.y);
    trans[xq * 4 + 2][c] = f2b(f.z);
    trans[xq * 4 + 3][c] = f2b(f.w);
  }
  __syncthreads();
  for (int i = t; i < 2 * CN / 8; i += 256) {
    int side = i >> 4, j = i & 15;
    ((uint4*)(dst + (size_t)side * (WP - 1) * CN))[j] = make_uint4(0, 0, 0, 0);
  }
  for (int i = t; i < WN * CN / 8; i += 256) {
    int xw = i >> 4, cq = (i & 15) * 8;
    ((uint4*)(dst + CN))[i] = *(const uint4*)&trans[xw][cq];
  }
}

// Async-corner kernel: raw bf16 corners via global_load_lds, 4 MFMA per tap,
// bilinear weights folded post-MFMA (linearity of matmul).
__global__ __launch_bounds__(256, 3)
void k_fused(const float* __restrict__ b_off, const float* __restrict__ b_def,
             const float* __restrict__ ln_w, const float* __restrict__ ln_b,
             const float* __restrict__ w_dw, const float* __restrict__ b_dw,
             const float* __restrict__ b_pw, float* __restrict__ out) {
  // dbuf[2][corner 0..3][px 0..15][128c] = 16384 u16 (32KB), linear layout;
  // patch [3][18][128] (6912 u16) aliases dbuf[0] during phases A/B.
  __shared__ __align__(16) uint16_t dbuf[2][4][16][128];
  __shared__ __align__(16) uint16_t dwT[2048];
  __shared__ float offarena[288];   // offl[18][16]; epilogue red/mu/rs alias
  __shared__ int   addrI[9 * 16 * 4];   // per (tap,px): 4 corner bases
  __shared__ float wgtF[9 * 16 * 4];    // per (tap,px): 4 bilinear weights
  float (*offl)[TILE] = (float (*)[TILE])offarena;
  float (*red1)[TILE] = (float (*)[TILE])offarena;
  float (*red2)[TILE] = (float (*)[TILE])(offarena + 64);
  float* muv = offarena + 128;
  float* rsv = offarena + 144;
  uint16_t* patch = &dbuf[0][0][0][0];

  int bid = blockIdx.x;
  int wid = (bid & 7) * (NWG / 8) + (bid >> 3);
  int wt = wid % NWT;
  int h  = (wid / NWT) % HN;
  int b  = wid / (NWT * HN);
  int w0 = wt * TILE;

  int t = (int)threadIdx.x;
  int l = t & 63, w = t >> 6;
  int g = l >> 4, fr = l & 15;
  int p = t & 15, cg = t >> 4;
  const uint16_t* xb = g_xp + (size_t)b * HP * WP * CN;

  // ---- phase A: stage 3x18 pixel-records -> patch (r15 verbatim) -----------
  #pragma unroll
  for (int rep = 0; rep < 4; ++rep) {
    int e = t + 256 * rep;
    if (e < 864) {
      int rec = e >> 4, chunk = e & 15;
      int ky = rec / 18, i = rec - 18 * ky;
      const uint16_t* src = xb + ((size_t)(h + ky) * WP + (w0 + i)) * CN + chunk * 8;
      *(uint4*)&patch[((ky * 18 + i) << 7) + swz(i, chunk * 8)] = *(const uint4*)src;
    }
  }
  __syncthreads();                            // barrier 1

  // ---- phase B1: offsets conv MFMA (waves 0,1; r15 verbatim) ---------------
  if (w < 2) {
    f32x4 aco = {0.f, 0.f, 0.f, 0.f};
    #pragma unroll
    for (int ks = 0; ks < 36; ++ks) {
      int kk = ks >> 2;
      int ky = kk / 3, kx = kk - 3 * ky;
      int cb = ((ks & 3) << 5) + (g << 3);
      int i = fr + kx;
      bf16x8 a = *(const bf16x8*)&g_off[(w * 16 + fr) * 1152 + (ks << 5) + (g << 3)];
      bf16x8 bb = *(const bf16x8*)&patch[((ky * 18 + i) << 7) + swz(i, cb)];
      aco = __builtin_amdgcn_mfma_f32_16x16x32_bf16(a, bb, aco, 0, 0, 0);
    }
    #pragma unroll
    for (int reg = 0; reg < 4; ++reg) {
      int j = w * 16 + g * 4 + reg;
      if (j < OFFC) offl[j][fr] = aco[reg] + b_off[j];
    }
  }

  // ---- phase B2: depthwise 3x3 + residual (r15 verbatim) -> regs -----------
  float adw[8];
  {
    int c0 = cg * 8;
    #pragma unroll
    for (int cl = 0; cl < 8; ++cl) adw[cl] = b_dw[c0 + cl];
    #pragma unroll
    for (int ky = 0; ky < 3; ++ky) {
      #pragma unroll
      for (int kx = 0; kx < 3; ++kx) {
        int i = p + kx;
        uint32_t r[4];
        *(uint4*)&r[0] = *(const uint4*)&patch[((ky * 18 + i) << 7) + swz(i, c0)];
        #pragma unroll
        for (int c2 = 0; c2 < 4; ++c2) {
          adw[2 * c2]     += lo16(r[c2]) * w_dw[(c0 + 2 * c2) * 9 + ky * 3 + kx];
          adw[2 * c2 + 1] += hi16(r[c2]) * w_dw[(c0 + 2 * c2 + 1) * 9 + ky * 3 + kx];
        }
      }
    }
    int i = p + 1;
    uint32_t r[4];
    *(uint4*)&r[0] = *(const uint4*)&patch[((18 + i) << 7) + swz(i, c0)];
    #pragma unroll
    for (int c2 = 0; c2 < 4; ++c2) {
      adw[2 * c2]     += lo16(r[c2]);
      adw[2 * c2 + 1] += hi16(r[c2]);
    }
  }
  __syncthreads();                            // barrier 2: patch reads done

  // ---- phase P: per-(tap,px) corner bases + weights; dwT write -------------
  if (t < 144) {
    int k = t >> 4, px = t & 15;
    int ky = k / 3, kx = k - 3 * ky;
    float dy = offl[2 * k][px], dx = offl[2 * k + 1][px];
    float ys = (float)(h - 1 + ky) + dy;
    float xs = (float)(w0 + px - 1 + kx) + dx;
    float y0f = floorf(ys), x0f = floorf(xs);
    float fy = ys - y0f, fx = xs - x0f;
    int y0 = (int)y0f, x0 = (int)x0f;
    float w00 = (1.f - fy) * (1.f - fx), w01 = (1.f - fy) * fx;
    float w10 = fy * (1.f - fx),         w11 = fy * fx;
    bool yok0 = (y0 >= 0) & (y0 < HN), yok1 = (y0 + 1 >= 0) & (y0 + 1 < HN);
    bool xok0 = (x0 >= 0) & (x0 < WN), xok1 = (x0 + 1 >= 0) & (x0 + 1 < WN);
    if (!(yok0 & xok0)) w00 = 0.f;
    if (!(yok0 & xok1)) w01 = 0.f;
    if (!(yok1 & xok0)) w10 = 0.f;
    if (!(yok1 & xok1)) w11 = 0.f;
    int ya  = min(max(y0, -1), HN) + 1;
    int yb2 = min(max(y0 + 1, -1), HN) + 1;
    int xa  = min(max(x0, -1), WN) + 1;
    int xc2 = min(max(x0 + 1, -1), WN) + 1;
    int e = (k * 16 + px) * 4;
    addrI[e + 0] = ya * WP + xa;
    addrI[e + 1] = ya * WP + xc2;
    addrI[e + 2] = yb2 * WP + xa;
    addrI[e + 3] = yb2 * WP + xc2;
    wgtF[e + 0] = w00; wgtF[e + 1] = w01; wgtF[e + 2] = w10; wgtF[e + 3] = w11;
  }
  {
    uint4 u = { pk2(adw[0], adw[1]), pk2(adw[2], adw[3]),
                pk2(adw[4], adw[5]), pk2(adw[6], adw[7]) };
    *(uint4*)&dwT[(p << 7) + swz(p, cg * 8)] = u;
  }
  __syncthreads();                            // barrier 2b: tables+dwT ready

  // async issue: wave w loads corner w of tap k into dbuf[buf]
  // LDS dest linear; SOURCE chunk pre-swizzled (rule #21) so reads use swz().
  auto ISSUE = [&](int k, int buf) {
    uint16_t* dst = &dbuf[buf][w][0][0];
    #pragma unroll
    for (int i = 0; i < 4; ++i) {
      int px = i * 4 + (l >> 4);
      int base = addrI[(k * 16 + px) * 4 + w];
      int gch = (l & 15) ^ (px & 7);
      const uint16_t* src = xb + (size_t)base * CN + gch * 8;
      gload16(src, dst + i * 512);
    }
  };

  // ---- prologue: issue tap 0, then pw MFMA + SiLU under its flight ---------
  ISSUE(0, 0);
  f32x4 a4[2];
  a4[0] = (f32x4){0.f, 0.f, 0.f, 0.f};
  a4[1] = (f32x4){0.f, 0.f, 0.f, 0.f};
  {
    #pragma unroll
    for (int ks = 0; ks < 4; ++ks) {
      int kb = (ks << 5) + (g << 3);
      bf16x8 a0 = *(const bf16x8*)&g_pw[(32 * w + fr) * 128 + kb];
      bf16x8 a1 = *(const bf16x8*)&g_pw[(32 * w + 16 + fr) * 128 + kb];
      bf16x8 bb = *(const bf16x8*)&dwT[(fr << 7) + swz(fr, kb)];
      a4[0] = __builtin_amdgcn_mfma_f32_16x16x32_bf16(a0, bb, a4[0], 0, 0, 0);
      a4[1] = __builtin_amdgcn_mfma_f32_16x16x32_bf16(a1, bb, a4[1], 0, 0, 0);
    }
    #pragma unroll
    for (int toc = 0; toc < 2; ++toc)
      #pragma unroll
      for (int reg = 0; reg < 4; ++reg) {
        int oc = 32 * w + 16 * toc + 4 * g + reg;
        float v = a4[toc][reg] + b_pw[oc];
        a4[toc][reg] = v / (1.f + __expf(-v));
      }
  }
  __syncthreads();    // barrier 3: drains tap-0 async loads (vmcnt(0))

  // ---- phase D: 9 taps; 4 corner-MFMAs + weight-combine; issue-ahead -------
  f32x4 ac1[2];
  ac1[0] = (f32x4){0.f, 0.f, 0.f, 0.f};
  ac1[1] = (f32x4){0.f, 0.f, 0.f, 0.f};
  #pragma unroll 1
  for (int k = 0; k < 9; ++k) {
    int buf = k & 1;
    if (k < 8) ISSUE(k + 1, buf ^ 1);   // async; overlaps MFMAs below
    f32x4 C[4][2];
    #pragma unroll
    for (int j = 0; j < 4; ++j) {
      C[j][0] = (f32x4){0.f, 0.f, 0.f, 0.f};
      C[j][1] = (f32x4){0.f, 0.f, 0.f, 0.f};
    }
    const uint16_t* gdk = g_def + (k << 14);
    #pragma unroll
    for (int ks = 0; ks < 4; ++ks) {
      int kb = (ks << 5) + (g << 3);
      bf16x8 a0 = *(const bf16x8*)&gdk[(32 * w + fr) * 128 + kb];
      bf16x8 a1 = *(const bf16x8*)&gdk[(32 * w + 16 + fr) * 128 + kb];
      #pragma unroll
      for (int j = 0; j < 4; ++j) {
        bf16x8 bb = *(const bf16x8*)&dbuf[buf][j][0][(fr << 7) + swz(fr, kb)];
        C[j][0] = __builtin_amdgcn_mfma_f32_16x16x32_bf16(a0, bb, C[j][0], 0, 0, 0);
        C[j][1] = __builtin_amdgcn_mfma_f32_16x16x32_bf16(a1, bb, C[j][1], 0, 0, 0);
      }
    }
    {  // weight-combine: lane's px = fr (C/D col = lane&15)
      int e = (k * 16 + fr) * 4;
      float q0 = wgtF[e], q1 = wgtF[e + 1], q2 = wgtF[e + 2], q3 = wgtF[e + 3];
      #pragma unroll
      for (int toc = 0; toc < 2; ++toc)
        #pragma unroll
        for (int reg = 0; reg < 4; ++reg)
          ac1[toc][reg] += q0 * C[0][toc][reg] + q1 * C[1][toc][reg]
                         + q2 * C[2][toc][reg] + q3 * C[3][toc][reg];
    }
    __syncthreads();   // vmcnt(0) drain: tap k+1 corners landed; buf reusable
  }

  // ---- phase E: bias + LayerNorm + add + store (r15 verbatim) --------------
  #pragma unroll
  for (int toc = 0; toc < 2; ++toc)
    #pragma unroll
    for (int reg = 0; reg < 4; ++reg) {
      int oc = 32 * w + 16 * toc + 4 * g + reg;
      ac1[toc][reg] += b_def[oc];
    }
  {
    float a = 0.f, q = 0.f;
    #pragma unroll
    for (int toc = 0; toc < 2; ++toc)
      #pragma unroll
      for (int reg = 0; reg < 4; ++reg) {
        float v = ac1[toc][reg];
        a += v; q += v * v;
      }
    a += __shfl_xor(a, 16); a += __shfl_xor(a, 32);
    q += __shfl_xor(q, 16); q += __shfl_xor(q, 32);
    if (l < 16) { red1[w][l] = a; red2[w][l] = q; }
  }
  __syncthreads();
  if (t < TILE) {
    float m = (red1[0][t] + red1[1][t] + red1[2][t] + red1[3][t]) * (1.f / 128.f);
    float q = (red2[0][t] + red2[1][t] + red2[2][t] + red2[3][t]) * (1.f / 128.f) - m * m;
    muv[t] = m;
    rsv[t] = rsqrtf(q + EPSV);
  }
  __syncthreads();
  {
    float mm = muv[fr], rr = rsv[fr];
    #pragma unroll
    for (int toc = 0; toc < 2; ++toc)
      #pragma unroll
      for (int reg = 0; reg < 4; ++reg) {
        int oc = 32 * w + 16 * toc + 4 * g + reg;
        float v = (ac1[toc][reg] - mm) * rr * ln_w[oc] + ln_b[oc] + a4[toc][reg];
        out[((size_t)(b * OCN + oc) * HN + h) * WN + w0 + fr] = v;
      }
  }
}

extern "C" void kernel_launch(void* const* d_in, const int* in_sizes, int n_in,
                              void* d_out, int out_size, void* d_ws, size_t ws_size,
                              hipStream_t stream) {
  const float* x     = (const float*)d_in[0];
  const float* w_off = (const float*)d_in[1];
  const float* b_off = (const float*)d_in[2];
  const float* w_def = (const float*)d_in[3];
  const float* b_def = (const float*)d_in[4];
  const float* ln_w  = (const float*)d_in[5];
  const float* ln_b  = (const float*)d_in[6];
  const float* w_dw  = (const float*)d_in[7];
  const float* b_dw  = (const float*)d_in[8];
  const float* w_pw  = (const float*)d_in[9];
  const float* b_pw  = (const float*)d_in[10];
  float* out = (float*)d_out;

  hipLaunchKernelGGL(k_prep_w, dim3(784), dim3(256), 0, stream, w_def, w_pw, w_off);
  hipLaunchKernelGGL(k_prep_x, dim3(BN * HP), dim3(256), 0, stream, x);
  hipLaunchKernelGGL(k_fused, dim3(NWG), dim3(256), 0, stream,
                     b_off, b_def, ln_w, ln_b, w_dw, b_dw, b_pw, out);
}

// Round 22
// 106.445 us; speedup vs baseline: 1.3272x; 1.3272x over previous
//
#include <hip/hip_runtime.h>
#include <hip/hip_bf16.h>
#include <stdint.h>

#define BN 4
#define CN 128
#define HN 96
#define WN 96
#define HW (HN*WN)
#define OCN 128
#define OFFC 18
#define EPSV 1e-6f
#define HP 98
#define WP 98

typedef __attribute__((ext_vector_type(8))) short bf16x8;
typedef __attribute__((ext_vector_type(4))) float f32x4;

__device__ __forceinline__ float lo16(uint32_t u) {
  union { uint32_t i; float f; } v; v.i = u << 16; return v.f;
}
__device__ __forceinline__ float hi16(uint32_t u) {
  union { uint32_t i; float f; } v; v.i = u & 0xffff0000u; return v.f;
}
__device__ __forceinline__ uint16_t f2b(float f) {
  union { float f; uint32_t i; } u; u.f = f;
  uint32_t r = u.i + 0x7fffu + ((u.i >> 16) & 1u);   // RNE
  return (uint16_t)(r >> 16);
}
__device__ __forceinline__ uint32_t pk2(float a, float b) {
  return (uint32_t)f2b(a) | ((uint32_t)f2b(b) << 16);
}
// LDS chunk swizzle: XOR 16B-chunk index with row low bits (T2-style)
__device__ __forceinline__ int swz(int row, int c) { return c ^ ((row & 7) << 3); }

// Persistent device-side prepped data (rewritten every launch; deterministic).
__device__ __align__(16) uint16_t g_def[9 * 128 * 128];   // [k][oc][c]
__device__ __align__(16) uint16_t g_pw[128 * 128];        // [oc][c]
__device__ __align__(16) uint16_t g_off[32 * 1152];       // [j(pad32)][kk*128+c]
__device__ __align__(16) uint16_t g_xp[(size_t)BN * HP * WP * CN];  // channels-last, 1px zero pad

// Merged prep: blocks 0..783 = weight transpose/cast; 784..1175 = x transpose.
__global__ __launch_bounds__(256)
void k_prep(const float* __restrict__ x,
            const float* __restrict__ w_def, const float* __restrict__ w_pw,
            const float* __restrict__ w_off) {
  __shared__ uint16_t trans[96][136];     // used by x-prep blocks only
  int bid = blockIdx.x;
  int t = (int)threadIdx.x;
  if (bid < 784) {
    int i = bid * 256 + t;
    if (i < 147456) {                     // 9*128*128
      int k = i >> 14, rem = i & 16383, oc = rem >> 7, c = rem & 127;
      g_def[i] = f2b(w_def[((oc << 7) + c) * 9 + k]);
    } else if (i < 147456 + 16384) {
      int j = i - 147456;
      g_pw[j] = f2b(w_pw[j]);
    } else if (i < 147456 + 16384 + 36864) {
      int j = i - 163840;
      int row = j / 1152, col = j - row * 1152;
      int kk = col >> 7, c = col & 127;
      g_off[j] = (row < OFFC) ? f2b(w_off[((row << 7) + c) * 9 + kk]) : (uint16_t)0;
    }
    return;
  }
  int blk = bid - 784;                    // 0..BN*HP-1
  int y1 = blk % HP;
  int b  = blk / HP;
  uint16_t* dst = g_xp + ((size_t)(b * HP + y1) * WP) * CN;
  if (y1 == 0 || y1 == HP - 1) {
    for (int i = t; i < WP * CN / 8; i += 256)
      ((uint4*)dst)[i] = make_uint4(0, 0, 0, 0);
    return;
  }
  int y = y1 - 1;
  for (int i = t; i < CN * WN / 4; i += 256) {     // coalesced fp32 reads
    int c = i / 24, xq = i - c * 24;
    float4 f = *(const float4*)&x[((size_t)(b * CN + c) * HN + y) * WN + xq * 4];
    trans[xq * 4 + 0][c] = f2b(f.x);
    trans[xq * 4 + 1][c] = f2b(f.y);
    trans[xq * 4 + 2][c] = f2b(f.z);
    trans[xq * 4 + 3][c] = f2b(f.w);
  }
  __syncthreads();
  for (int i = t; i < 2 * CN / 8; i += 256) {      // x-border zeros
    int side = i >> 4, j = i & 15;
    ((uint4*)(dst + (size_t)side * (WP - 1) * CN))[j] = make_uint4(0, 0, 0, 0);
  }
  for (int i = t; i < WN * CN / 8; i += 256) {     // contiguous bf16 row write
    int xw = i >> 4, cq = (i & 15) * 8;
    ((uint4*)(dst + CN))[i] = *(const uint4*)&trans[xw][cq];
  }
}

__global__ __launch_bounds__(256, 2)
void k_fused(const float* __restrict__ b_off, const float* __restrict__ b_def,
             const float* __restrict__ ln_w, const float* __restrict__ ln_b,
             const float* __restrict__ w_dw, const float* __restrict__ b_dw,
             const float* __restrict__ b_pw, float* __restrict__ out) {
  // patch: [ky 0..2][i 0..33][128c] bf16, chunk-swizzled (13056 elems, 26112B).
  // Aliases once all patch reads complete (after barrier 2):
  //   s0 = [0,4096), s1 = [4096,8192), s2 = [8192,12288).
  __shared__ __align__(16) uint16_t patch[3 * 34 * 128];
  __shared__ __align__(16) uint16_t dwT[4096];
  __shared__ float offarena[576];   // offl[18][32] during taps; red/mu/rs after
  float (*offl)[32] = (float (*)[32])offarena;
  float (*red1)[32] = (float (*)[32])offarena;
  float (*red2)[32] = (float (*)[32])(offarena + 128);
  float* muv = offarena + 256;
  float* rsv = offarena + 288;
  uint16_t* sbuf[3] = { patch, patch + 4096, patch + 8192 };

  int bid = blockIdx.x;
  int wid = (bid & 7) * 144 + (bid >> 3);     // XCD-chunked swizzle (1152 = 8*144)
  int wt = wid % 3;
  int h  = (wid / 3) % HN;
  int b  = wid / (3 * HN);
  int w0 = wt * 32;

  int t = (int)threadIdx.x;
  int l = t & 63, w = t >> 6;
  int g = l >> 4, fr = l & 15;
  int p = t & 31, cg = t >> 5;
  const uint16_t* xb = g_xp + (size_t)b * HP * WP * CN;
  int cbase = w * 32 + (l & 3) * 8;           // gather: this lane's 8-ch chunk
  const uint16_t* bp = xb + cbase;

  // ---- phase A: stage 3x34 pixel-records (bf16, contiguous) -> patch -------
  #pragma unroll
  for (int rep = 0; rep < 7; ++rep) {
    int e = t + 256 * rep;                    // 1632 16B-chunks total
    if (e < 1632) {
      int rec = e >> 4, chunk = e & 15;
      int ky = rec / 34, i = rec - 34 * ky;
      const uint16_t* src = xb + ((size_t)(h + ky) * WP + (w0 + i)) * CN + chunk * 8;
      *(uint4*)&patch[((ky * 34 + i) << 7) + swz(i, chunk * 8)] = *(const uint4*)src;
    }
  }
  __syncthreads();                            // barrier 1

  // ---- phase B1: offsets conv MFMA (A from g_off, B from patch) ------------
  {
    int toc = w >> 1, tp = w & 1;
    f32x4 aco = {0.f, 0.f, 0.f, 0.f};
    #pragma unroll
    for (int ks = 0; ks < 36; ++ks) {
      int kk = ks >> 2;
      int ky = kk / 3, kx = kk - 3 * ky;
      int cb = ((ks & 3) << 5) + (g << 3);
      int i = fr + (tp << 4) + kx;
      bf16x8 a = *(const bf16x8*)&g_off[(toc * 16 + fr) * 1152 + (ks << 5) + (g << 3)];
      bf16x8 bb = *(const bf16x8*)&patch[((ky * 34 + i) << 7) + swz(i, cb)];
      aco = __builtin_amdgcn_mfma_f32_16x16x32_bf16(a, bb, aco, 0, 0, 0);
    }
    #pragma unroll
    for (int reg = 0; reg < 4; ++reg) {
      int j = toc * 16 + g * 4 + reg;
      if (j < OFFC) offl[j][(tp << 4) + fr] = aco[reg] + b_off[j];
    }
  }

  // ---- phase B2: depthwise 3x3 + residual (from patch) -> regs -------------
  float adw[16];
  {
    #pragma unroll
    for (int cl = 0; cl < 16; ++cl) adw[cl] = b_dw[cg * 16 + cl];
    #pragma unroll
    for (int ky = 0; ky < 3; ++ky) {
      #pragma unroll
      for (int kx = 0; kx < 3; ++kx) {
        int i = p + kx;
        uint32_t r[8];
        *(uint4*)&r[0] = *(const uint4*)&patch[((ky * 34 + i) << 7) + swz(i, cg * 16)];
        *(uint4*)&r[4] = *(const uint4*)&patch[((ky * 34 + i) << 7) + swz(i, cg * 16 + 8)];
        #pragma unroll
        for (int c2 = 0; c2 < 8; ++c2) {
          adw[2 * c2]     += lo16(r[c2]) * w_dw[(cg * 16 + 2 * c2) * 9 + ky * 3 + kx];
          adw[2 * c2 + 1] += hi16(r[c2]) * w_dw[(cg * 16 + 2 * c2 + 1) * 9 + ky * 3 + kx];
        }
      }
    }
    int i = p + 1;                             // + x residual (center)
    uint32_t r[8];
    *(uint4*)&r[0] = *(const uint4*)&patch[((34 + i) << 7) + swz(i, cg * 16)];
    *(uint4*)&r[4] = *(const uint4*)&patch[((34 + i) << 7) + swz(i, cg * 16 + 8)];
    #pragma unroll
    for (int c2 = 0; c2 < 8; ++c2) {
      adw[2 * c2]     += lo16(r[c2]);
      adw[2 * c2 + 1] += hi16(r[c2]);
    }
  }
  __syncthreads();    // barrier 2: ALL patch reads done -> s-buffers writable

  // fused gather (round-8-proven): loads + lerp + LDS write
  auto GATHER = [&](int kk, uint16_t* wb) {
    int ky = kk / 3, kx = kk - 3 * ky;
    #pragma unroll
    for (int half = 0; half < 2; ++half) {
      int px = half * 16 + (l >> 2);
      float dy = offl[2 * kk][px], dx = offl[2 * kk + 1][px];
      float ys = (float)(h - 1 + ky) + dy;
      float xs = (float)(w0 + px - 1 + kx) + dx;
      float y0f = floorf(ys), x0f = floorf(xs);
      float fy = ys - y0f, fx = xs - x0f;
      int y0 = (int)y0f, x0 = (int)x0f;
      float w00 = (1.f - fy) * (1.f - fx), w01 = (1.f - fy) * fx;
      float w10 = fy * (1.f - fx),         w11 = fy * fx;
      bool yok0 = (y0 >= 0) & (y0 < HN), yok1 = (y0 + 1 >= 0) & (y0 + 1 < HN);
      bool xok0 = (x0 >= 0) & (x0 < WN), xok1 = (x0 + 1 >= 0) & (x0 + 1 < WN);
      if (!(yok0 & xok0)) w00 = 0.f;
      if (!(yok0 & xok1)) w01 = 0.f;
      if (!(yok1 & xok0)) w10 = 0.f;
      if (!(yok1 & xok1)) w11 = 0.f;
      int ya  = min(max(y0, -1), HN) + 1;      // clamped padded coords
      int yb2 = min(max(y0 + 1, -1), HN) + 1;
      int xa  = min(max(x0, -1), WN) + 1;
      int xc2 = min(max(x0 + 1, -1), WN) + 1;
      uint32_t A[4], B[4], C[4], D[4];
      *(uint4*)A = *(const uint4*)(bp + ((size_t)ya * WP + xa) * CN);
      *(uint4*)B = *(const uint4*)(bp + ((size_t)ya * WP + xc2) * CN);
      *(uint4*)C = *(const uint4*)(bp + ((size_t)yb2 * WP + xa) * CN);
      *(uint4*)D = *(const uint4*)(bp + ((size_t)yb2 * WP + xc2) * CN);
      uint32_t pk4[4];
      #pragma unroll
      for (int q2 = 0; q2 < 4; ++q2) {
        float s0 = w00 * lo16(A[q2]) + w01 * lo16(B[q2]) + w10 * lo16(C[q2]) + w11 * lo16(D[q2]);
        float s1 = w00 * hi16(A[q2]) + w01 * hi16(B[q2]) + w10 * hi16(C[q2]) + w11 * hi16(D[q2]);
        pk4[q2] = pk2(s0, s1);
      }
      *(uint4*)&wb[(px << 7) + swz(px, cbase)] = *(uint4*)pk4;
    }
  };

  // accumulate one tap's MFMAs from LDS buffer rb
  f32x4 ac1[2][2];
  #pragma unroll
  for (int q1 = 0; q1 < 2; ++q1)
    #pragma unroll
    for (int q2 = 0; q2 < 2; ++q2) ac1[q1][q2] = (f32x4){0.f, 0.f, 0.f, 0.f};
  auto TAPMM = [&](int k, const uint16_t* rb) {
    const uint16_t* gdk = g_def + (k << 14);
    #pragma unroll
    for (int ks = 0; ks < 4; ++ks) {
      int kb = (ks << 5) + (g << 3);
      bf16x8 a0 = *(const bf16x8*)&gdk[(32 * w + fr) * 128 + kb];
      bf16x8 a1 = *(const bf16x8*)&gdk[(32 * w + 16 + fr) * 128 + kb];
      #pragma unroll
      for (int tp2 = 0; tp2 < 2; ++tp2) {
        int pp = (tp2 << 4) + fr;
        bf16x8 bb = *(const bf16x8*)&rb[(pp << 7) + swz(pp, kb)];
        ac1[0][tp2] = __builtin_amdgcn_mfma_f32_16x16x32_bf16(a0, bb, ac1[0][tp2], 0, 0, 0);
        ac1[1][tp2] = __builtin_amdgcn_mfma_f32_16x16x32_bf16(a1, bb, ac1[1][tp2], 0, 0, 0);
      }
    }
  };

  // ---- W0: write dwT + gather taps 0..2 (24 loads/wave in flight) ----------
  {
    #pragma unroll
    for (int m = 0; m < 2; ++m) {
      uint4 u = { pk2(adw[8*m+0], adw[8*m+1]), pk2(adw[8*m+2], adw[8*m+3]),
                  pk2(adw[8*m+4], adw[8*m+5]), pk2(adw[8*m+6], adw[8*m+7]) };
      *(uint4*)&dwT[(p << 7) + swz(p, cg * 16 + 8 * m)] = u;
    }
    GATHER(0, sbuf[0]);
    GATHER(1, sbuf[1]);
    GATHER(2, sbuf[2]);
  }
  __syncthreads();                            // barrier 3

  // ---- R0: pointwise 1x1 MFMA + SiLU, plus taps 0..2 ------------------------
  f32x4 a4[2][2];
  #pragma unroll
  for (int q1 = 0; q1 < 2; ++q1)
    #pragma unroll
    for (int q2 = 0; q2 < 2; ++q2) a4[q1][q2] = (f32x4){0.f, 0.f, 0.f, 0.f};
  {
    #pragma unroll
    for (int ks = 0; ks < 4; ++ks) {
      int kb = (ks << 5) + (g << 3);
      bf16x8 a0 = *(const bf16x8*)&g_pw[(32 * w + fr) * 128 + kb];
      bf16x8 a1 = *(const bf16x8*)&g_pw[(32 * w + 16 + fr) * 128 + kb];
      #pragma unroll
      for (int tp2 = 0; tp2 < 2; ++tp2) {
        int pp = (tp2 << 4) + fr;
        bf16x8 bb = *(const bf16x8*)&dwT[(pp << 7) + swz(pp, kb)];
        a4[0][tp2] = __builtin_amdgcn_mfma_f32_16x16x32_bf16(a0, bb, a4[0][tp2], 0, 0, 0);
        a4[1][tp2] = __builtin_amdgcn_mfma_f32_16x16x32_bf16(a1, bb, a4[1][tp2], 0, 0, 0);
      }
    }
    TAPMM(0, sbuf[0]);
    TAPMM(1, sbuf[1]);
    TAPMM(2, sbuf[2]);
    #pragma unroll
    for (int toc2 = 0; toc2 < 2; ++toc2)
      #pragma unroll
      for (int tp2 = 0; tp2 < 2; ++tp2)
        #pragma unroll
        for (int reg = 0; reg < 4; ++reg) {
          int oc = 32 * w + 16 * toc2 + 4 * g + reg;
          float v = a4[toc2][tp2][reg] + b_pw[oc];
          a4[toc2][tp2][reg] = v / (1.f + __expf(-v));
        }
  }
  __syncthreads();                            // barrier 4

  // ---- groups 1,2: strict W/R alternation -----------------------------------
  #pragma unroll 1
  for (int grp = 1; grp < 3; ++grp) {
    GATHER(3 * grp + 0, sbuf[0]);
    GATHER(3 * grp + 1, sbuf[1]);
    GATHER(3 * grp + 2, sbuf[2]);
    __syncthreads();                          // W done
    TAPMM(3 * grp + 0, sbuf[0]);
    TAPMM(3 * grp + 1, sbuf[1]);
    TAPMM(3 * grp + 2, sbuf[2]);
    __syncthreads();                          // R done
  }

  // ---- phase E: bias + LayerNorm + add + store -----------------------------
  #pragma unroll
  for (int toc2 = 0; toc2 < 2; ++toc2)
    #pragma unroll
    for (int tp2 = 0; tp2 < 2; ++tp2)
      #pragma unroll
      for (int reg = 0; reg < 4; ++reg) {
        int oc = 32 * w + 16 * toc2 + 4 * g + reg;
        ac1[toc2][tp2][reg] += b_def[oc];
      }
  {
    float s1[2], s2[2];
    #pragma unroll
    for (int tp2 = 0; tp2 < 2; ++tp2) {
      float a = 0.f, q = 0.f;
      #pragma unroll
      for (int toc2 = 0; toc2 < 2; ++toc2)
        #pragma unroll
        for (int reg = 0; reg < 4; ++reg) {
          float v = ac1[toc2][tp2][reg];
          a += v; q += v * v;
        }
      a += __shfl_xor(a, 16); a += __shfl_xor(a, 32);
      q += __shfl_xor(q, 16); q += __shfl_xor(q, 32);
      s1[tp2] = a; s2[tp2] = q;
    }
    if (l < 16) {
      red1[w][l] = s1[0]; red1[w][l + 16] = s1[1];
      red2[w][l] = s2[0]; red2[w][l + 16] = s2[1];
    }
  }
  __syncthreads();
  if (t < 32) {
    float m = (red1[0][t] + red1[1][t] + red1[2][t] + red1[3][t]) * (1.f / 128.f);
    float q = (red2[0][t] + red2[1][t] + red2[2][t] + red2[3][t]) * (1.f / 128.f) - m * m;
    muv[t] = m;
    rsv[t] = rsqrtf(q + EPSV);
  }
  __syncthreads();
  {
    #pragma unroll
    for (int toc2 = 0; toc2 < 2; ++toc2)
      #pragma unroll
      for (int tp2 = 0; tp2 < 2; ++tp2) {
        int pp = (tp2 << 4) + fr;
        float mm = muv[pp], rr = rsv[pp];
        #pragma unroll
        for (int reg = 0; reg < 4; ++reg) {
          int oc = 32 * w + 16 * toc2 + 4 * g + reg;
          float v = (ac1[toc2][tp2][reg] - mm) * rr * ln_w[oc] + ln_b[oc]
                    + a4[toc2][tp2][reg];
          out[((size_t)(b * OCN + oc) * HN + h) * WN + w0 + pp] = v;
        }
      }
  }
}

extern "C" void kernel_launch(void* const* d_in, const int* in_sizes, int n_in,
                              void* d_out, int out_size, void* d_ws, size_t ws_size,
                              hipStream_t stream) {
  const float* x     = (const float*)d_in[0];
  const float* w_off = (const float*)d_in[1];
  const float* b_off = (const float*)d_in[2];
  const float* w_def = (const float*)d_in[3];
  const float* b_def = (const float*)d_in[4];
  const float* ln_w  = (const float*)d_in[5];
  const float* ln_b  = (const float*)d_in[6];
  const float* w_dw  = (const float*)d_in[7];
  const float* b_dw  = (const float*)d_in[8];
  const float* w_pw  = (const float*)d_in[9];
  const float* b_pw  = (const float*)d_in[10];
  float* out = (float*)d_out;

  hipLaunchKernelGGL(k_prep, dim3(784 + BN * HP), dim3(256), 0, stream,
                     x, w_def, w_pw, w_off);
  hipLaunchKernelGGL(k_fused, dim3(BN * HN * 3), dim3(256), 0, stream,
                     b_off, b_def, ln_w, ln_b, w_dw, b_dw, b_pw, out);
}